// Round 11
// baseline (218.900 us; speedup 1.0000x reference)
//
#include <hip/hip_runtime.h>
#include <math.h>

#define G  17
#define Cg 32
#define B  4
#define C  544
#define H  96
#define W  96
#define HW (H*W)
#define TILES 36         // 6x6 tiles of 16x16 px
#define NBLK (B*G*TILES) // 2448 (divisible by 8)
#define BN_EPS 1e-5f

typedef float    f32x4  __attribute__((ext_vector_type(4)));
typedef short    short8 __attribute__((ext_vector_type(8)));
typedef _Float16 h2     __attribute__((ext_vector_type(2)));
typedef _Float16 h8     __attribute__((ext_vector_type(8)));

// ---- deform LDS layout (round-10 verified: deform ~55us) ----
#define WIN       20
#define HALO      2
#define WPOS      (WIN*WIN)       // 400
#define W_STRIDE  80
#define W_BYTES   (WPOS*W_STRIDE) // 32000
#define B_STRIDE  592
#define B_BYTES   (Cg*B_STRIDE)   // 18944
#define SMEM_BYTES (W_BYTES + B_BYTES) // 50944 -> 3 blocks/CU

// ---- offset-conv LDS layout ----
// 18x18 window (16x16 tile + conv halo 1), 32 f32/pos, stride 33 dwords:
// consecutive positions -> consecutive bank starts (conflict-free).
#define OW       18
#define OPOS     (OW*OW)          // 324
#define OSTRIDE  33               // dwords

// XCD-chunked swizzle (round-4 verified: FETCH 925->87 MB).
__device__ __forceinline__ int swizzle_blk(int blk) {
    return (blk & 7) * (NBLK / 8) + (blk >> 3);
}

// ---------------------------------------------------------------------------
// Kernel 1 (tile): stage 18x18x32 f32 x-window (ZERO-padded) in LDS once;
//  (a) grouped 3x3 offset conv from LDS -> aff (no bounds checks in loop),
//  (b) fp16 channels-last xT emitted from the same window (kills transpose
//      kernel AND the round-10 fusion's occupancy problem: 49.7KB -> 3 blk/CU
//      with LDS-local reads, vs 41KB + global-latency at 4 blk/CU).
// ---------------------------------------------------------------------------
__global__ __launch_bounds__(256) void offset_tile_kernel(
    const float* __restrict__ x, const float* __restrict__ w_off,
    const float* __restrict__ b_off, float* __restrict__ aff,
    _Float16* __restrict__ xT)
{
    __shared__ float ws[OPOS*OSTRIDE];     // 42768 B
    __shared__ float wl[Cg*9*6];           // 6912 B   (total 49680 B)

    const int blk  = swizzle_blk(blockIdx.x);
    const int tile = blk % TILES;
    const int g    = (blk / TILES) % G;
    const int b    = blk / (TILES*G);
    const int ty   = tile / 6, tx = tile % 6;
    const int h0   = ty*16,    w0 = tx*16;
    const int tid  = threadIdx.x;

    // ---- stage conv weights: wl[i][t][c] ----
    for (int l = tid; l < Cg*9*6; l += 256) {
        int c = l % 6; int t = (l/6) % 9; int i = l/54;
        wl[l] = w_off[(size_t)(g*6 + c)*(Cg*9) + i*9 + t];
    }

    // ---- stage x window: zero-padded (conv semantics), ch-outer so
    //      consecutive threads read consecutive columns (coalesced) ----
    const float* xg = x + ((size_t)b*C + g*Cg)*HW;
    for (int idx = tid; idx < OPOS*Cg; idx += 256) {
        const int ch  = idx / OPOS, pos = idx % OPOS;
        const int wy  = pos / OW,   wx  = pos % OW;
        const int y   = h0 + wy - 1, xx = w0 + wx - 1;
        const bool v  = (y >= 0) && (y < H) && (xx >= 0) && (xx < W);
        ws[pos*OSTRIDE + ch] = v ? xg[(size_t)ch*HW + y*W + xx] : 0.0f;
    }
    __syncthreads();   // single barrier

    // ---- offset conv from LDS: thread = pixel (row,col) of 16x16 tile ----
    const int row = tid >> 4, col = tid & 15;
    float acc[6];
    #pragma unroll
    for (int c = 0; c < 6; ++c) acc[c] = b_off[g*6 + c];

    for (int i = 0; i < Cg; ++i) {
        #pragma unroll
        for (int t = 0; t < 9; ++t) {
            const int wpos = (row + t/3)*OW + (col + t%3);
            const float v = ws[wpos*OSTRIDE + i];
            #pragma unroll
            for (int c = 0; c < 6; ++c)
                acc[c] = fmaf(v, wl[(i*9 + t)*6 + c], acc[c]);
        }
    }

    const int p = (h0 + row)*W + (w0 + col);
    float* ap = aff + ((size_t)(b*G + g)*6)*HW + p;
    #pragma unroll
    for (int c = 0; c < 6; ++c) ap[(size_t)c*HW] = acc[c];

    // ---- emit fp16 channels-last xT from the window (inner 16x16) ----
    _Float16* xTg = xT + (size_t)(b*G + g)*HW*Cg;
    #pragma unroll
    for (int r = 0; r < 4; ++r) {
        const int idx = r*256 + tid;           // px = idx>>2, ch8 = idx&3
        const int px  = idx >> 2, ch8 = (idx & 3)*8;
        const int py  = px >> 4,  pxc = px & 15;
        const float* s = &ws[((py + 1)*OW + (pxc + 1))*OSTRIDE + ch8];
        h8 o;
        #pragma unroll
        for (int j = 0; j < 8; ++j) o[j] = (_Float16)s[j];
        *(h8*)(xTg + ((size_t)(h0 + py)*W + (w0 + pxc))*Cg + ch8) = o;
    }
}

// ---------------------------------------------------------------------------
// Kernel 2: LDS-window fp16 MFMA deformable conv + BN + residual ReLU.
// (unchanged from round 10: ~55us, verified)
// ---------------------------------------------------------------------------
__global__ __launch_bounds__(256) void deform_mfma_kernel(
    const float* __restrict__ x, const _Float16* __restrict__ xT,
    const float* __restrict__ w_def, const float* __restrict__ aff,
    const float* __restrict__ gamma, const float* __restrict__ beta,
    const float* __restrict__ rmean, const float* __restrict__ rvar,
    float* __restrict__ out)
{
    __shared__ __align__(16) char smem[SMEM_BYTES];
    char* Wsm = smem;            // window
    char* Bsm = smem + W_BYTES;  // weights

    const int blk  = swizzle_blk(blockIdx.x);
    const int tile = blk % TILES;
    const int g    = (blk / TILES) % G;
    const int b    = blk / (TILES*G);
    const int ty   = tile / 6, tx = tile % 6;
    const int h0   = ty*16,    w0 = tx*16;
    const int tid  = threadIdx.x;
    const int lane = tid & 63;
    const int wv   = tid >> 6;
    const int r15  = lane & 15;
    const int koff = lane >> 4;

    const _Float16* xgT_base = xT + (size_t)(b*G + g)*HW*Cg;

    // ---- stage window to LDS: 400 pos x 64B, border-clamped ----
    for (int i = tid; i < WPOS*4; i += 256) {
        const int pos = i >> 2, ch = (i & 3)*8;
        const int wy = pos / WIN, wx = pos % WIN;
        const int y  = min(max(h0 + wy - HALO, 0), H-1);
        const int xx = min(max(w0 + wx - HALO, 0), W-1);
        *(short8*)(Wsm + pos*W_STRIDE + ch*2) =
            *(const short8*)(xgT_base + ((size_t)y*W + xx)*Cg + ch);
    }
    // ---- stage group weights to LDS (fp16): Bsm[o][K=t*32+i] ----
    for (int l = tid; l < Cg*288; l += 256) {
        const int o = l / 288, K = l % 288;
        const int t = K >> 5, i = K & 31;
        const float wt = w_def[(size_t)(g*Cg + o)*(Cg*9) + i*9 + t];
        *(_Float16*)(Bsm + o*B_STRIDE + K*2) = (_Float16)wt;
    }
    __syncthreads();   // the only barrier

    // ---- per-lane: affine params + coords for its 4 pixels ----
    const float* afb = aff + ((size_t)(b*G + g)*6)*HW;
    float a0[4], a1[4], a2[4], a3[4], a4[4], a5[4];
    float hf[4], wf[4];
    #pragma unroll
    for (int m = 0; m < 4; ++m) {
        const int row = wv*4 + m;
        const int p = (h0 + row)*W + w0 + r15;
        a0[m] = afb[0*(size_t)HW + p];
        a1[m] = afb[1*(size_t)HW + p];
        a2[m] = afb[2*(size_t)HW + p];
        a3[m] = afb[3*(size_t)HW + p];
        a4[m] = afb[4*(size_t)HW + p];
        a5[m] = afb[5*(size_t)HW + p];
        hf[m] = (float)(h0 + row);
        wf[m] = (float)(w0 + r15);
    }

    const _Float16* xgT = xgT_base + koff*8;
    const int kb = koff*16;   // byte offset of this lane's 8-ch slice

    f32x4 acc[4][2];
    #pragma unroll
    for (int m = 0; m < 4; ++m)
        #pragma unroll
        for (int n = 0; n < 2; ++n)
            acc[m][n] = (f32x4){0.f, 0.f, 0.f, 0.f};

    #pragma unroll 1
    for (int t = 0; t < 9; ++t) {
        const float kyf = (float)(t/3 - 1);
        const float kxf = (float)(t%3 - 1);

        h8 af[4];
        #pragma unroll
        for (int m = 0; m < 4; ++m) {
            const float py = hf[m] + kyf + (a0[m]*kyf + a1[m]*kxf + a2[m]);
            const float px = wf[m] + kxf + (a3[m]*kyf + a4[m]*kxf + a5[m]);
            const float y0f = floorf(py), x0f = floorf(px);
            const float fy = py - y0f,   fx = px - x0f;
            const int y0 = (int)y0f, x0 = (int)x0f;
            const int y1 = y0 + 1,   x1 = x0 + 1;
            const bool vy0 = (y0 >= 0) && (y0 < H);
            const bool vy1 = (y1 >= 0) && (y1 < H);
            const bool vx0 = (x0 >= 0) && (x0 < W);
            const bool vx1 = (x1 >= 0) && (x1 < W);
            const float w00f = (vy0 && vx0) ? (1.0f - fy)*(1.0f - fx) : 0.0f;
            const float w01f = (vy0 && vx1) ? (1.0f - fy)*fx          : 0.0f;
            const float w10f = (vy1 && vx0) ? fy*(1.0f - fx)          : 0.0f;
            const float w11f = (vy1 && vx1) ? fy*fx                   : 0.0f;
            const int y0c = min(max(y0, 0), H-1), y1c = min(max(y1, 0), H-1);
            const int x0c = min(max(x0, 0), W-1), x1c = min(max(x1, 0), W-1);

            const int wy0 = y0c - h0 + HALO, wy1 = y1c - h0 + HALO;
            const int wx0 = x0c - w0 + HALO, wx1 = x1c - w0 + HALO;
            const bool ok = ((unsigned)wy0 < WIN) & ((unsigned)wy1 < WIN)
                          & ((unsigned)wx0 < WIN) & ((unsigned)wx1 < WIN);

            union { short8 s; h2 h[4]; h8 v; } u00, u01, u10, u11, r;
            if (__builtin_expect(ok, 1)) {
                u00.s = *(const short8*)(Wsm + (wy0*WIN + wx0)*W_STRIDE + kb);
                u01.s = *(const short8*)(Wsm + (wy0*WIN + wx1)*W_STRIDE + kb);
                u10.s = *(const short8*)(Wsm + (wy1*WIN + wx0)*W_STRIDE + kb);
                u11.s = *(const short8*)(Wsm + (wy1*WIN + wx1)*W_STRIDE + kb);
            } else {
                u00.s = *(const short8*)(xgT + (size_t)(y0c*W + x0c)*Cg);
                u01.s = *(const short8*)(xgT + (size_t)(y0c*W + x1c)*Cg);
                u10.s = *(const short8*)(xgT + (size_t)(y1c*W + x0c)*Cg);
                u11.s = *(const short8*)(xgT + (size_t)(y1c*W + x1c)*Cg);
            }

            const _Float16 W00 = (_Float16)w00f, W01 = (_Float16)w01f;
            const _Float16 W10 = (_Float16)w10f, W11 = (_Float16)w11f;
            #pragma unroll
            for (int j = 0; j < 4; ++j)
                r.h[j] = W00*u00.h[j] + W01*u01.h[j] + W10*u10.h[j] + W11*u11.h[j];
            af[m] = r.v;
        }

        #pragma unroll
        for (int n = 0; n < 2; ++n) {
            const h8 bf = *(const h8*)(Bsm + (n*16 + r15)*B_STRIDE + t*64 + kb);
            #pragma unroll
            for (int m = 0; m < 4; ++m)
                acc[m][n] = __builtin_amdgcn_mfma_f32_16x16x32_f16(af[m], bf, acc[m][n], 0, 0, 0);
        }
    }

    // ---- epilogue: BN + residual + ReLU, 16B-chunk stores ----
    #pragma unroll
    for (int m = 0; m < 4; ++m) {
        const int row = wv*4 + m;
        const int pxg = (h0 + row)*W + w0 + koff*4;     // D row=(lane>>4)*4+reg
        #pragma unroll
        for (int n = 0; n < 2; ++n) {
            const int o = n*16 + r15;
            const int c = g*Cg + o;
            const float inv   = rsqrtf(rvar[c] + BN_EPS);
            const float scale = inv * gamma[c];
            const float shift = beta[c] - rmean[c]*scale;
            const size_t base = ((size_t)b*C + c)*HW + pxg;
            const float4 res = *(const float4*)(x + base);
            float4 ov;
            ov.x = fmaxf(acc[m][n][0]*scale + shift + res.x, 0.0f);
            ov.y = fmaxf(acc[m][n][1]*scale + shift + res.y, 0.0f);
            ov.z = fmaxf(acc[m][n][2]*scale + shift + res.z, 0.0f);
            ov.w = fmaxf(acc[m][n][3]*scale + shift + res.w, 0.0f);
            *(float4*)(out + base) = ov;
        }
    }
}

// ---------------------------------------------------------------------------
// Fallback pair (NCHW f32 path) if ws is too small for aff + xT.
// ---------------------------------------------------------------------------
__global__ __launch_bounds__(256) void offset_conv_kernel(
    const float* __restrict__ x, const float* __restrict__ w_off,
    const float* __restrict__ b_off, float* __restrict__ aff)
{
    __shared__ float wl[Cg*9*6];
    const int blk  = swizzle_blk(blockIdx.x);
    const int tile = blk % TILES;
    const int g    = (blk / TILES) % G;
    const int b    = blk / (TILES*G);

    for (int l = threadIdx.x; l < Cg*9*6; l += 256) {
        int c = l % 6; int t = (l/6) % 9; int i = l/54;
        wl[l] = w_off[(size_t)(g*6 + c)*(Cg*9) + i*9 + t];
    }
    __syncthreads();

    const int p = tile*256 + threadIdx.x;
    const int h = p / W, w = p % W;

    float acc[6];
    #pragma unroll
    for (int c = 0; c < 6; ++c) acc[c] = b_off[g*6 + c];

    const float* xg = x + ((size_t)b*C + g*Cg)*HW;
    for (int i = 0; i < Cg; ++i) {
        const float* xc = xg + (size_t)i*HW;
        #pragma unroll
        for (int t = 0; t < 9; ++t) {
            const int dy = t/3 - 1, dx = t%3 - 1;
            const int yy = h + dy, xx = w + dx;
            float v = (yy >= 0 && yy < H && xx >= 0 && xx < W) ? xc[yy*W + xx] : 0.0f;
            #pragma unroll
            for (int c = 0; c < 6; ++c)
                acc[c] = fmaf(v, wl[(i*9 + t)*6 + c], acc[c]);
        }
    }

    float* ap = aff + ((size_t)(b*G + g)*6)*HW + p;
    #pragma unroll
    for (int c = 0; c < 6; ++c) ap[(size_t)c*HW] = acc[c];
}

__global__ __launch_bounds__(256) void deform_conv_kernel(
    const float* __restrict__ x, const float* __restrict__ w_def,
    const float* __restrict__ aff, const float* __restrict__ gamma,
    const float* __restrict__ beta, const float* __restrict__ rmean,
    const float* __restrict__ rvar, float* __restrict__ out)
{
    __shared__ float wl[9*Cg*Cg];
    const int blk  = swizzle_blk(blockIdx.x);
    const int tile = blk % TILES;
    const int g    = (blk / TILES) % G;
    const int b    = blk / (TILES*G);

    for (int l = threadIdx.x; l < 9*Cg*Cg; l += 256) {
        int o = l & 31; int i = (l >> 5) & 31; int k = l >> 10;
        wl[l] = w_def[(size_t)(g*Cg + o)*(Cg*9) + i*9 + k];
    }
    __syncthreads();

    const int p = tile*256 + threadIdx.x;
    const int h = p / W, w = p % W;

    const float* ap = aff + ((size_t)(b*G + g)*6)*HW + p;
    const float a0 = ap[0*(size_t)HW], a1 = ap[1*(size_t)HW], a2 = ap[2*(size_t)HW];
    const float a3 = ap[3*(size_t)HW], a4 = ap[4*(size_t)HW], a5 = ap[5*(size_t)HW];

    float acc[Cg];
    #pragma unroll
    for (int o = 0; o < Cg; ++o) acc[o] = 0.0f;

    const float* xg = x + ((size_t)b*C + g*Cg)*HW;

    #pragma unroll
    for (int k = 0; k < 9; ++k) {
        const float kyf = (float)(k/3 - 1);
        const float kxf = (float)(k%3 - 1);
        const float offy = a0*kyf + a1*kxf + a2;
        const float offx = a3*kyf + a4*kxf + a5;
        const float py = (float)h + kyf + offy;
        const float px = (float)w + kxf + offx;
        const float y0f = floorf(py), x0f = floorf(px);
        const float fy = py - y0f,   fx = px - x0f;
        const int y0 = (int)y0f, x0 = (int)x0f;
        const int y1 = y0 + 1,   x1 = x0 + 1;
        const bool vy0 = (y0 >= 0) && (y0 < H);
        const bool vy1 = (y1 >= 0) && (y1 < H);
        const bool vx0 = (x0 >= 0) && (x0 < W);
        const bool vx1 = (x1 >= 0) && (x1 < W);
        const float w00 = (vy0 && vx0) ? (1.0f - fy)*(1.0f - fx) : 0.0f;
        const float w01 = (vy0 && vx1) ? (1.0f - fy)*fx          : 0.0f;
        const float w10 = (vy1 && vx0) ? fy*(1.0f - fx)          : 0.0f;
        const float w11 = (vy1 && vx1) ? fy*fx                   : 0.0f;
        const int y0c = min(max(y0, 0), H-1), y1c = min(max(y1, 0), H-1);
        const int x0c = min(max(x0, 0), W-1), x1c = min(max(x1, 0), W-1);
        const int p00 = y0c*W + x0c, p01 = y0c*W + x1c;
        const int p10 = y1c*W + x0c, p11 = y1c*W + x1c;

        const float* wk = &wl[k*Cg*Cg];
        for (int i = 0; i < Cg; ++i) {
            const float* xc = xg + (size_t)i*HW;
            const float v = w00*xc[p00] + w01*xc[p01] + w10*xc[p10] + w11*xc[p11];
            #pragma unroll
            for (int o = 0; o < Cg; ++o)
                acc[o] = fmaf(v, wk[i*Cg + o], acc[o]);
        }
    }

    float* op = out + ((size_t)b*C + g*Cg)*HW + p;
    #pragma unroll
    for (int o = 0; o < Cg; ++o) {
        const int c = g*Cg + o;
        const float inv = rsqrtf(rvar[c] + BN_EPS);
        float val = (acc[o] - rmean[c]) * (inv * gamma[c]) + beta[c];
        val += xg[(size_t)o*HW + p];
        op[(size_t)o*HW] = fmaxf(val, 0.0f);
    }
}

// ---------------------------------------------------------------------------
extern "C" void kernel_launch(void* const* d_in, const int* in_sizes, int n_in,
                              void* d_out, int out_size, void* d_ws, size_t ws_size,
                              hipStream_t stream) {
    const float* x     = (const float*)d_in[0];
    const float* w_off = (const float*)d_in[1];
    const float* b_off = (const float*)d_in[2];
    const float* w_def = (const float*)d_in[3];
    const float* gamma = (const float*)d_in[4];
    const float* beta  = (const float*)d_in[5];
    const float* rmean = (const float*)d_in[6];
    const float* rvar  = (const float*)d_in[7];
    float* out = (float*)d_out;

    const size_t AFF_BYTES = (size_t)B*G*6*HW*sizeof(float);       // ~15.0 MB
    const size_t XT_BYTES  = (size_t)B*G*HW*Cg*sizeof(_Float16);   // ~40.1 MB
    float* aff = (float*)d_ws;

    if (ws_size >= AFF_BYTES + XT_BYTES) {
        _Float16* xT = (_Float16*)((char*)d_ws + AFF_BYTES);
        offset_tile_kernel<<<NBLK, 256, 0, stream>>>(x, w_off, b_off, aff, xT);
        deform_mfma_kernel<<<NBLK, 256, 0, stream>>>(x, xT, w_def, aff, gamma,
                                                     beta, rmean, rvar, out);
    } else {
        offset_conv_kernel<<<NBLK, 256, 0, stream>>>(x, w_off, b_off, aff);
        deform_conv_kernel<<<NBLK, 256, 0, stream>>>(x, w_def, aff, gamma, beta,
                                                     rmean, rvar, out);
    }
}